// Round 4
// baseline (905.066 us; speedup 1.0000x reference)
//
#include <hip/hip_runtime.h>

// Problem constants
#define SEQ   2048
#define NHEAD 16
#define NKV   4
#define HDIM  128
#define NB    4
// qkv_raw row layout: [qg 0..4095 | k 4096..4607 | v 4608..5119]
#define QKVW  5120

typedef unsigned short u16;
typedef unsigned int   u32;
typedef __bf16 v8bf __attribute__((ext_vector_type(8)));
typedef float  v4f  __attribute__((ext_vector_type(4)));

__device__ __forceinline__ u16 f2bf(float f) {
  u32 u = __float_as_uint(f);
  u += 0x7fffu + ((u >> 16) & 1u);
  return (u16)(u >> 16);
}
__device__ __forceinline__ float bf2f(u16 b) {
  return __uint_as_float(((u32)b) << 16);
}

// Async global->LDS DMA, 16B per lane. LDS dest must be linear in lane order
// (wave-uniform base + lane*16).
__device__ __forceinline__ void gld_lds16(const u16* g, u16* l) {
  __builtin_amdgcn_global_load_lds(
      (const __attribute__((address_space(1))) u32*)(unsigned long long)(uintptr_t)g,
      (__attribute__((address_space(3))) u32*)(u32)(uintptr_t)l,
      16, 0, 0);
}

// ---------------------------------------------------------------------------
// fp32 -> bf16 bulk convert (8 elems/thread)
__global__ __launch_bounds__(256) void conv_f32_bf16(const float* __restrict__ s,
                                                     u16* __restrict__ d) {
  size_t i = ((size_t)blockIdx.x * 256 + threadIdx.x) * 8;
  float4 a = *(const float4*)(s + i);
  float4 b = *(const float4*)(s + i + 4);
  uint4 o;
  o.x = (u32)f2bf(a.x) | ((u32)f2bf(a.y) << 16);
  o.y = (u32)f2bf(a.z) | ((u32)f2bf(a.w) << 16);
  o.z = (u32)f2bf(b.x) | ((u32)f2bf(b.y) << 16);
  o.w = (u32)f2bf(b.z) | ((u32)f2bf(b.w) << 16);
  *(uint4*)(d + i) = o;
}

// ---------------------------------------------------------------------------
// fp32 source -> bf16 transposed dst: dst[c*R + r] = bf16(src[r*C + c])
// grid (C/64, R/64), block 256.
__global__ __launch_bounds__(256) void transpose_w(const float* __restrict__ src,
                                                   u16* __restrict__ dst,
                                                   int R, int C) {
  __shared__ u16 tile[64][80];
  int t = threadIdx.x;
  int r0 = blockIdx.y * 64, c0 = blockIdx.x * 64;
  int rr = t >> 2, cc = (t & 3) * 16;
  const float* sp = src + (size_t)(r0 + rr) * C + c0 + cc;
  float4 f0 = *(const float4*)sp;
  float4 f1 = *(const float4*)(sp + 4);
  float4 f2 = *(const float4*)(sp + 8);
  float4 f3 = *(const float4*)(sp + 12);
  u16* tp = &tile[rr][cc];
  tp[0] = f2bf(f0.x);  tp[1] = f2bf(f0.y);  tp[2] = f2bf(f0.z);  tp[3] = f2bf(f0.w);
  tp[4] = f2bf(f1.x);  tp[5] = f2bf(f1.y);  tp[6] = f2bf(f1.z);  tp[7] = f2bf(f1.w);
  tp[8] = f2bf(f2.x);  tp[9] = f2bf(f2.y);  tp[10] = f2bf(f2.z); tp[11] = f2bf(f2.w);
  tp[12] = f2bf(f3.x); tp[13] = f2bf(f3.y); tp[14] = f2bf(f3.z); tp[15] = f2bf(f3.w);
  __syncthreads();
  int cr = t >> 2, rc = (t & 3) * 16;
  u32 pk[8];
#pragma unroll
  for (int i = 0; i < 8; i++) {
    u32 lo = tile[rc + 2 * i][cr];
    u32 hi = tile[rc + 2 * i + 1][cr];
    pk[i] = lo | (hi << 16);
  }
  u16* dp = dst + (size_t)(c0 + cr) * R + r0 + rc;
  uint4 o0 = {pk[0], pk[1], pk[2], pk[3]};
  uint4 o1 = {pk[4], pk[5], pk[6], pk[7]};
  *(uint4*)dp       = o0;
  *(uint4*)(dp + 8) = o1;
}

// ---------------------------------------------------------------------------
// V transpose (bf16->bf16): vt[((b*NKV+g)*HDIM + d)*SEQ + s]
// grid (SEQ/64, HDIM/64, NB*NKV), block 256
__global__ __launch_bounds__(256) void transpose_v(const u16* __restrict__ qkv,
                                                   u16* __restrict__ vt) {
  __shared__ u16 tile[64][80];
  int t = threadIdx.x;
  int s0 = blockIdx.x * 64;
  int d0 = blockIdx.y * 64;
  int bg = blockIdx.z;
  int b = bg >> 2, g = bg & 3;
  int sr = t >> 2, dc = (t & 3) * 16;
  const u16* sp = qkv + (size_t)(b * SEQ + s0 + sr) * QKVW + 4608 + g * HDIM + d0 + dc;
  *(uint4*)&tile[sr][dc]     = *(const uint4*)sp;
  *(uint4*)&tile[sr][dc + 8] = *(const uint4*)(sp + 8);
  __syncthreads();
  int dr = t >> 2, sc = (t & 3) * 16;
  u32 pk[8];
#pragma unroll
  for (int i = 0; i < 8; i++) {
    u32 lo = tile[sc + 2 * i][dr];
    u32 hi = tile[sc + 2 * i + 1][dr];
    pk[i] = lo | (hi << 16);
  }
  u16* dp = vt + ((size_t)bg * HDIM + d0 + dr) * SEQ + s0 + sc;
  uint4 o0 = {pk[0], pk[1], pk[2], pk[3]};
  uint4 o1 = {pk[4], pk[5], pk[6], pk[7]};
  *(uint4*)dp       = o0;
  *(uint4*)(dp + 8) = o1;
}

// ---------------------------------------------------------------------------
// GEMM: C[M,N] = A[M,K] * Bt[N,K]^T, bf16 in, fp32 accum.
// 128x128 block tile, 4 waves (2x2 of 64x64), MFMA 16x16x32_bf16, BK=32.
// 2-PHASE double-buffered pipeline (T3 minimum): stage tile t+1 via
// global_load_lds into buf^1 BEFORE computing tile t; single barrier per
// K-step whose implicit vmcnt(0) drain lands AFTER the compute, so the
// HBM/L2 latency of the stage hides under 16 MFMA + 8 ds_read_b128.
template <bool OUT_F32>
__global__ __launch_bounds__(256) void gemm_bt(const u16* __restrict__ A,
                                               const u16* __restrict__ Bt,
                                               void* __restrict__ Cp,
                                               int M, int N, int K) {
  __shared__ u16 As[2][128 * 32];
  __shared__ u16 Bs[2][128 * 32];
  int tid  = threadIdx.x;
  int lane = tid & 63, wave = tid >> 6;
  int wr = wave >> 1, wc = wave & 1;
  int col = lane & 15, quad = lane >> 4;
  int m0 = blockIdx.y * 128, n0 = blockIdx.x * 128;

  v4f acc[4][4];
#pragma unroll
  for (int mi = 0; mi < 4; mi++)
#pragma unroll
    for (int ni = 0; ni < 4; ni++) acc[mi][ni] = (v4f){0.f, 0.f, 0.f, 0.f};

  int srow = tid >> 2;            // 0..63
  int skc  = (tid & 3) * 8;       // 0,8,16,24
  const u16* ag0 = A  + (size_t)(m0 + srow) * K + skc;
  const u16* ag1 = ag0 + (size_t)64 * K;
  const u16* bg0 = Bt + (size_t)(n0 + srow) * K + skc;
  const u16* bg1 = bg0 + (size_t)64 * K;

  // prologue: stage tile 0 into buffer 0
  gld_lds16(ag0, &As[0][tid * 8]);
  gld_lds16(ag1, &As[0][2048 + tid * 8]);
  gld_lds16(bg0, &Bs[0][tid * 8]);
  gld_lds16(bg1, &Bs[0][2048 + tid * 8]);
  __syncthreads();

  int nt = K >> 5;
  for (int t = 0; t < nt; ++t) {
    int cur = t & 1, nxt = cur ^ 1;
    if (t + 1 < nt) {
      int k0 = (t + 1) << 5;
      gld_lds16(ag0 + k0, &As[nxt][tid * 8]);
      gld_lds16(ag1 + k0, &As[nxt][2048 + tid * 8]);
      gld_lds16(bg0 + k0, &Bs[nxt][tid * 8]);
      gld_lds16(bg1 + k0, &Bs[nxt][2048 + tid * 8]);
    }
    v8bf a[4], bb[4];
#pragma unroll
    for (int mi = 0; mi < 4; mi++)
      a[mi] = *(const v8bf*)&As[cur][(wr * 64 + mi * 16 + col) * 32 + quad * 8];
#pragma unroll
    for (int ni = 0; ni < 4; ni++)
      bb[ni] = *(const v8bf*)&Bs[cur][(wc * 64 + ni * 16 + col) * 32 + quad * 8];
    __builtin_amdgcn_s_setprio(1);
#pragma unroll
    for (int mi = 0; mi < 4; mi++)
#pragma unroll
      for (int ni = 0; ni < 4; ni++)
        acc[mi][ni] = __builtin_amdgcn_mfma_f32_16x16x32_bf16(a[mi], bb[ni], acc[mi][ni], 0, 0, 0);
    __builtin_amdgcn_s_setprio(0);
    __syncthreads();   // drains stage (vmcnt 0) + protects buf reuse
  }

  // epilogue: C/D layout row = quad*4+reg, col = lane&15
#pragma unroll
  for (int mi = 0; mi < 4; mi++)
#pragma unroll
    for (int ni = 0; ni < 4; ni++) {
      int r_ = m0 + wr * 64 + mi * 16 + quad * 4;
      int c_ = n0 + wc * 64 + ni * 16 + col;
#pragma unroll
      for (int r = 0; r < 4; r++) {
        if (OUT_F32) ((float*)Cp)[(size_t)(r_ + r) * N + c_] = acc[mi][ni][r];
        else         ((u16*)Cp)[(size_t)(r_ + r) * N + c_]   = f2bf(acc[mi][ni][r]);
      }
    }
}

// ---------------------------------------------------------------------------
// RMS-norm (+ 1+w) + RoPE. q normed IN PLACE in qkv_raw; k written to
// head-major kf. One wave per (token, head-row).
__global__ __launch_bounds__(256) void norm_rope(u16* __restrict__ qkv,
                                                 const float* __restrict__ cosb,
                                                 const float* __restrict__ sinb,
                                                 const float* __restrict__ qw,
                                                 const float* __restrict__ kw,
                                                 u16* __restrict__ kf) {
  int wave = threadIdx.x >> 6, lane = threadIdx.x & 63;
  int tw = blockIdx.x * 4 + wave;
  int token = tw / 20, r = tw % 20;
  const u16* src;
  u16* dst;
  const float* wptr;
  if (r < 16) {
    src  = qkv + (size_t)token * QKVW + r * 256;       // q of head r
    dst  = (u16*)src;                                  // in place
    wptr = qw;
  } else {
    src  = qkv + (size_t)token * QKVW + 4096 + (r - 16) * HDIM;
    int b = token >> 11, s = token & (SEQ - 1);
    dst  = kf + ((size_t)(b * NKV + (r - 16)) * SEQ + s) * HDIM;
    wptr = kw;
  }
  int d0 = lane * 2;
  u32 x = *(const u32*)(src + d0);
  float x0 = bf2f((u16)(x & 0xffff)), x1 = bf2f((u16)(x >> 16));
  float ss = x0 * x0 + x1 * x1;
#pragma unroll
  for (int off = 1; off < 64; off <<= 1) ss += __shfl_xor(ss, off, 64);
  float sc = rsqrtf(ss * (1.f / 128.f) + 1e-6f);
  float y0 = bf2f(f2bf(x0 * sc * (1.f + wptr[d0])));
  float y1 = bf2f(f2bf(x1 * sc * (1.f + wptr[d0 + 1])));
  float p0 = __shfl_xor(y0, 8, 64);
  float p1 = __shfl_xor(y1, 8, 64);
  float z0 = y0, z1 = y1;
  if (lane < 16) {
    float c0 = cosb[(size_t)token * 32 + d0];
    float c1 = cosb[(size_t)token * 32 + d0 + 1];
    float s0 = sinb[(size_t)token * 32 + d0];
    float s1 = sinb[(size_t)token * 32 + d0 + 1];
    if (lane < 8) { z0 = y0 * c0 - p0 * s0; z1 = y1 * c1 - p1 * s1; }
    else          { z0 = y0 * c0 + p0 * s0; z1 = y1 * c1 + p1 * s1; }
  }
  u32 outp = (u32)f2bf(z0) | ((u32)f2bf(z1) << 16);
  *(u32*)(dst + d0) = outp;
}

// ---------------------------------------------------------------------------
// Causal GQA flash attention + sigmoid-gate epilogue.
// Swapped-operand QK^T (mfma(K,Q)), in-register softmax, sigma-permuted V.
// T14 async-STAGE: tile t+1's K/V global loads issue into registers right
// after the post-staging barrier; the ds_writes happen at the top of the
// next iteration, so HBM latency hides under QK+softmax+PV of tile t.
// grid (32, NHEAD, NB), block 256.
__global__ __launch_bounds__(256) void attn_kernel(const u16* __restrict__ qkv,
                                                   const u16* __restrict__ kf,
                                                   const u16* __restrict__ vt,
                                                   u16* __restrict__ ga) {
  __shared__ u16 ks[64 * 136];      // K-tile [key][d], stride 136
  __shared__ u16 vs[128 * 88];      // V-tile [d][sigma(key)], stride 88
  int tid = threadIdx.x, lane = tid & 63, wave = tid >> 6;
  int col = lane & 15, quad = lane >> 4;
  int qt = 31 - blockIdx.x;         // heavy causal blocks first (LPT)
  int h = blockIdx.y, b = blockIdx.z;
  int g = h >> 2;
  int qw0 = qt * 64 + wave * 16;
  int myq = qw0 + col;              // this lane's query row
  const float scl2 = 0.08838834764831845f * 1.4426950408889634f;  // D^-.5 * log2e

  // Q fragments (B-layout: n=query=lane&15, k=quad*8+j)
  v8bf qfr[4];
  const u16* qbase = qkv + (size_t)(b * SEQ + myq) * QKVW + h * 256 + quad * 8;
#pragma unroll
  for (int kc = 0; kc < 4; kc++) qfr[kc] = *(const v8bf*)(qbase + kc * 32);

  v4f o[8];                         // O^T: o[dt][r] = O[d=16dt+4*quad+r][myq]
#pragma unroll
  for (int nt = 0; nt < 8; nt++) o[nt] = (v4f){0.f, 0.f, 0.f, 0.f};
  float l = 0.f;                    // per-quad partial row-sum (this lane's keys)
  float m = -1e30f;                 // running max (uniform across quads)

  const u16* kfb = kf + (size_t)(b * NKV + g) * SEQ * HDIM;
  const u16* vtb = vt + (size_t)(b * NKV + g) * HDIM * SEQ;

  int ksr = tid >> 4, ksd = (tid & 15) * 8;   // K staging map
  int vsd = tid >> 3, w8 = tid & 7;           // V staging map
  // sigma(s)=(s5,s3,s2,s4,s1,s0); src s = 8*w8 + i, w8 bits = (s5,s4,s3)
  int voff = 32 * ((w8 >> 2) & 1) + 16 * (w8 & 1) + 4 * ((w8 >> 1) & 1);
  int vsrc = w8 * 8;

  // prologue: issue tile-0 loads into registers
  uint4 kr[4], vr[4];
#pragma unroll
  for (int p = 0; p < 4; p++)
    kr[p] = *(const uint4*)&kfb[(size_t)(ksr + p * 16) * HDIM + ksd];
#pragma unroll
  for (int p = 0; p < 4; p++)
    vr[p] = *(const uint4*)&vtb[(size_t)(vsd + p * 32) * SEQ + vsrc];

  int nk = qt + 1;
  for (int it = 0; it < nk; it++) {
    int k0 = it * 64;
    __syncthreads();  // previous iteration's LDS reads complete
#pragma unroll
    for (int p = 0; p < 4; p++)
      *(uint4*)&ks[(ksr + p * 16) * 136 + ksd] = kr[p];
#pragma unroll
    for (int p = 0; p < 4; p++) {
      int d = vsd + p * 32;
      uint2 w0 = {vr[p].x, vr[p].y};
      uint2 w1 = {vr[p].z, vr[p].w};
      *(uint2*)&vs[d * 88 + voff]     = w0;   // keys i=0..3 -> voff..voff+3
      *(uint2*)&vs[d * 88 + voff + 8] = w1;   // keys i=4..7 -> voff+8..
    }
    __syncthreads();
    if (it + 1 < nk) {  // issue next tile's loads; latency hides under compute
      int kn = k0 + 64;
#pragma unroll
      for (int p = 0; p < 4; p++)
        kr[p] = *(const uint4*)&kfb[(size_t)(kn + ksr + p * 16) * HDIM + ksd];
#pragma unroll
      for (int p = 0; p < 4; p++)
        vr[p] = *(const uint4*)&vtb[(size_t)(vsd + p * 32) * SEQ + kn + vsrc];
    }

    // --- S^T = K Q^T: st[t][r] = S[key=k0+16t+4*quad+r][myq] ---
    v4f st[4];
    __builtin_amdgcn_s_setprio(1);
#pragma unroll
    for (int t = 0; t < 4; t++) {
      v4f acc = (v4f){0.f, 0.f, 0.f, 0.f};
#pragma unroll
      for (int kc = 0; kc < 4; kc++) {
        v8bf kfr = *(const v8bf*)&ks[(t * 16 + col) * 136 + kc * 32 + quad * 8];
        acc = __builtin_amdgcn_mfma_f32_16x16x32_bf16(kfr, qfr[kc], acc, 0, 0, 0);
      }
      st[t] = acc;
    }
    __builtin_amdgcn_s_setprio(0);

    // --- in-register online softmax (exp2 domain) ---
    bool diag = (it == nk - 1);
    float pmax = -1e30f;
#pragma unroll
    for (int t = 0; t < 4; t++)
#pragma unroll
      for (int r = 0; r < 4; r++) {
        float x = st[t][r] * scl2;
        if (diag && (k0 + t * 16 + quad * 4 + r > myq)) x = -1e30f;
        st[t][r] = x;
        pmax = fmaxf(pmax, x);
      }
    pmax = fmaxf(pmax, __shfl_xor(pmax, 16, 64));
    pmax = fmaxf(pmax, __shfl_xor(pmax, 32, 64));
    if (__any(pmax > m + 8.f)) {         // defer-max: rescale only on growth
      float nm = fmaxf(m, pmax);
      float al = exp2f(m - nm);
      m = nm;
#pragma unroll
      for (int nt = 0; nt < 8; nt++)
#pragma unroll
        for (int r = 0; r < 4; r++) o[nt][r] *= al;
      l *= al;
    }
    // P in bf16, packed directly in PV B-fragment order (lane-local)
    v8bf pb0, pb1;
    float ls = 0.f;
#pragma unroll
    for (int t = 0; t < 4; t++)
#pragma unroll
      for (int r = 0; r < 4; r++) {
        float p = exp2f(st[t][r] - m);
        ls += p;
        if (t < 2) pb0[t * 4 + r] = (__bf16)p;
        else       pb1[(t - 2) * 4 + r] = (__bf16)p;
      }
    l += ls;

    // --- O^T += V^T P : A=V-frag (m=d), B=P-frag (n=query) ---
    __builtin_amdgcn_s_setprio(1);
#pragma unroll
    for (int nt = 0; nt < 8; nt++) {
      v8bf vb0 = *(const v8bf*)&vs[(nt * 16 + col) * 88 + quad * 8];
      v8bf vb1 = *(const v8bf*)&vs[(nt * 16 + col) * 88 + 32 + quad * 8];
      o[nt] = __builtin_amdgcn_mfma_f32_16x16x32_bf16(vb0, pb0, o[nt], 0, 0, 0);
      o[nt] = __builtin_amdgcn_mfma_f32_16x16x32_bf16(vb1, pb1, o[nt], 0, 0, 0);
    }
    __builtin_amdgcn_s_setprio(0);
  }

  // --- final row-sum across quads, normalize, sigmoid-gate, store ---
  l += __shfl_xor(l, 16, 64);
  l += __shfl_xor(l, 32, 64);
  float inv = 1.f / l;
  const u16* gb = qkv + (size_t)(b * SEQ + myq) * QKVW + h * 256 + 128 + quad * 4;
  u16* ob = ga + (size_t)(b * SEQ + myq) * 2048 + h * HDIM + quad * 4;
#pragma unroll
  for (int nt = 0; nt < 8; nt++) {
    uint2 gw = *(const uint2*)(gb + nt * 16);
    float g0 = bf2f((u16)(gw.x & 0xffff)), g1 = bf2f((u16)(gw.x >> 16));
    float g2 = bf2f((u16)(gw.y & 0xffff)), g3 = bf2f((u16)(gw.y >> 16));
    float a0 = o[nt][0] * inv * (1.f / (1.f + expf(-g0)));
    float a1 = o[nt][1] * inv * (1.f / (1.f + expf(-g1)));
    float a2 = o[nt][2] * inv * (1.f / (1.f + expf(-g2)));
    float a3 = o[nt][3] * inv * (1.f / (1.f + expf(-g3)));
    uint2 ow;
    ow.x = (u32)f2bf(a0) | ((u32)f2bf(a1) << 16);
    ow.y = (u32)f2bf(a2) | ((u32)f2bf(a3) << 16);
    *(uint2*)(ob + nt * 16) = ow;
  }
}

// ---------------------------------------------------------------------------
extern "C" void kernel_launch(void* const* d_in, const int* in_sizes, int n_in,
                              void* d_out, int out_size, void* d_ws, size_t ws_size,
                              hipStream_t stream) {
  const float* hidden = (const float*)d_in[0];
  const float* cosb   = (const float*)d_in[1];
  const float* sinb   = (const float*)d_in[2];
  // d_in[3] attention_mask: exact causal triu(-1e9) -> applied analytically
  const float* wq  = (const float*)d_in[4];
  const float* wk  = (const float*)d_in[5];
  const float* wv  = (const float*)d_in[6];
  const float* wo  = (const float*)d_in[7];
  const float* qnw = (const float*)d_in[8];
  const float* knw = (const float*)d_in[9];
  float* out = (float*)d_out;

  u16* ws      = (u16*)d_ws;
  u16* qkv_raw = ws;
  u16* region2 = qkv_raw + (size_t)8192 * QKVW;
  u16* region3 = region2 + (size_t)8192 * 2048;
  u16* hidden_bf = region2;
  u16* g_attn    = region2;
  u16* bt_qkv    = region3;
  u16* vt        = region3;
  u16* bt_wo     = region3 + (size_t)4194304;
  u16* k_f       = region3 + (size_t)8388608;

  // 1) convert hidden fp32 -> bf16
  conv_f32_bf16<<<dim3(8192), 256, 0, stream>>>(hidden, hidden_bf);
  // 2) convert+transpose qkv weights into B^T bf16 (wq|wk|wv row-concat)
  transpose_w<<<dim3(64, 32), 256, 0, stream>>>(wq, bt_qkv, 2048, 4096);
  transpose_w<<<dim3(8, 32), 256, 0, stream>>>(wk, bt_qkv + (size_t)4096 * 2048, 2048, 512);
  transpose_w<<<dim3(8, 32), 256, 0, stream>>>(wv, bt_qkv + (size_t)4608 * 2048, 2048, 512);
  // 3) fused QKV projection (bf16 out)
  gemm_bt<false><<<dim3(QKVW / 128, 8192 / 128), 256, 0, stream>>>(hidden_bf, bt_qkv, qkv_raw, 8192, QKVW, 2048);
  // 4) RMS-norm + RoPE: q in place, k -> head-major k_f
  norm_rope<<<dim3(8192 * 20 / 4), 256, 0, stream>>>(qkv_raw, cosb, sinb, qnw, knw, k_f);
  // 5) V -> d-major vt (overwrites dead bt_qkv)
  transpose_v<<<dim3(SEQ / 64, HDIM / 64, NB * NKV), 256, 0, stream>>>(qkv_raw, vt);
  // 6) convert+transpose wo
  transpose_w<<<dim3(32, 32), 256, 0, stream>>>(wo, bt_wo, 2048, 2048);
  // 7) causal flash attention + gating (writes g_attn over dead hidden_bf)
  attn_kernel<<<dim3(32, NHEAD, NB), 256, 0, stream>>>(qkv_raw, k_f, vt, g_attn);
  // 8) output projection, fp32 store
  gemm_bt<true><<<dim3(2048 / 128, 8192 / 128), 256, 0, stream>>>(g_attn, bt_wo, out, 8192, 2048, 2048);
}

// Round 5
// 727.673 us; speedup vs baseline: 1.2438x; 1.2438x over previous
//
#include <hip/hip_runtime.h>

// Problem constants
#define SEQ   2048
#define NHEAD 16
#define NKV   4
#define HDIM  128
#define NB    4
// qkv_raw row layout: [qg 0..4095 | k 4096..4607 | v 4608..5119]
#define QKVW  5120

typedef unsigned short u16;
typedef unsigned int   u32;
typedef __bf16 v8bf __attribute__((ext_vector_type(8)));
typedef float  v4f  __attribute__((ext_vector_type(4)));

__device__ __forceinline__ u16 f2bf(float f) {
  u32 u = __float_as_uint(f);
  u += 0x7fffu + ((u >> 16) & 1u);
  return (u16)(u >> 16);
}
__device__ __forceinline__ float bf2f(u16 b) {
  return __uint_as_float(((u32)b) << 16);
}

// Async global->LDS DMA, 16B per lane. LDS dest must be linear in lane order
// (wave-uniform base + lane*16).
__device__ __forceinline__ void gld_lds16(const u16* g, u16* l) {
  __builtin_amdgcn_global_load_lds(
      (const __attribute__((address_space(1))) u32*)(unsigned long long)(uintptr_t)g,
      (__attribute__((address_space(3))) u32*)(u32)(uintptr_t)l,
      16, 0, 0);
}

// ---------------------------------------------------------------------------
// fp32 -> bf16 bulk convert (8 elems/thread)
__global__ __launch_bounds__(256) void conv_f32_bf16(const float* __restrict__ s,
                                                     u16* __restrict__ d) {
  size_t i = ((size_t)blockIdx.x * 256 + threadIdx.x) * 8;
  float4 a = *(const float4*)(s + i);
  float4 b = *(const float4*)(s + i + 4);
  uint4 o;
  o.x = (u32)f2bf(a.x) | ((u32)f2bf(a.y) << 16);
  o.y = (u32)f2bf(a.z) | ((u32)f2bf(a.w) << 16);
  o.z = (u32)f2bf(b.x) | ((u32)f2bf(b.y) << 16);
  o.w = (u32)f2bf(b.z) | ((u32)f2bf(b.w) << 16);
  *(uint4*)(d + i) = o;
}

// ---------------------------------------------------------------------------
// fp32 source -> bf16 transposed dst: dst[c*R + r] = bf16(src[r*C + c])
// grid (C/64, R/64), block 256.
__global__ __launch_bounds__(256) void transpose_w(const float* __restrict__ src,
                                                   u16* __restrict__ dst,
                                                   int R, int C) {
  __shared__ u16 tile[64][80];
  int t = threadIdx.x;
  int r0 = blockIdx.y * 64, c0 = blockIdx.x * 64;
  int rr = t >> 2, cc = (t & 3) * 16;
  const float* sp = src + (size_t)(r0 + rr) * C + c0 + cc;
  float4 f0 = *(const float4*)sp;
  float4 f1 = *(const float4*)(sp + 4);
  float4 f2 = *(const float4*)(sp + 8);
  float4 f3 = *(const float4*)(sp + 12);
  u16* tp = &tile[rr][cc];
  tp[0] = f2bf(f0.x);  tp[1] = f2bf(f0.y);  tp[2] = f2bf(f0.z);  tp[3] = f2bf(f0.w);
  tp[4] = f2bf(f1.x);  tp[5] = f2bf(f1.y);  tp[6] = f2bf(f1.z);  tp[7] = f2bf(f1.w);
  tp[8] = f2bf(f2.x);  tp[9] = f2bf(f2.y);  tp[10] = f2bf(f2.z); tp[11] = f2bf(f2.w);
  tp[12] = f2bf(f3.x); tp[13] = f2bf(f3.y); tp[14] = f2bf(f3.z); tp[15] = f2bf(f3.w);
  __syncthreads();
  int cr = t >> 2, rc = (t & 3) * 16;
  u32 pk[8];
#pragma unroll
  for (int i = 0; i < 8; i++) {
    u32 lo = tile[rc + 2 * i][cr];
    u32 hi = tile[rc + 2 * i + 1][cr];
    pk[i] = lo | (hi << 16);
  }
  u16* dp = dst + (size_t)(c0 + cr) * R + r0 + rc;
  uint4 o0 = {pk[0], pk[1], pk[2], pk[3]};
  uint4 o1 = {pk[4], pk[5], pk[6], pk[7]};
  *(uint4*)dp       = o0;
  *(uint4*)(dp + 8) = o1;
}

// ---------------------------------------------------------------------------
// V transpose (bf16->bf16): vt[((b*NKV+g)*HDIM + d)*SEQ + s]
// grid (SEQ/64, HDIM/64, NB*NKV), block 256
__global__ __launch_bounds__(256) void transpose_v(const u16* __restrict__ qkv,
                                                   u16* __restrict__ vt) {
  __shared__ u16 tile[64][80];
  int t = threadIdx.x;
  int s0 = blockIdx.x * 64;
  int d0 = blockIdx.y * 64;
  int bg = blockIdx.z;
  int b = bg >> 2, g = bg & 3;
  int sr = t >> 2, dc = (t & 3) * 16;
  const u16* sp = qkv + (size_t)(b * SEQ + s0 + sr) * QKVW + 4608 + g * HDIM + d0 + dc;
  *(uint4*)&tile[sr][dc]     = *(const uint4*)sp;
  *(uint4*)&tile[sr][dc + 8] = *(const uint4*)(sp + 8);
  __syncthreads();
  int dr = t >> 2, sc = (t & 3) * 16;
  u32 pk[8];
#pragma unroll
  for (int i = 0; i < 8; i++) {
    u32 lo = tile[sc + 2 * i][dr];
    u32 hi = tile[sc + 2 * i + 1][dr];
    pk[i] = lo | (hi << 16);
  }
  u16* dp = vt + ((size_t)bg * HDIM + d0 + dr) * SEQ + s0 + sc;
  uint4 o0 = {pk[0], pk[1], pk[2], pk[3]};
  uint4 o1 = {pk[4], pk[5], pk[6], pk[7]};
  *(uint4*)dp       = o0;
  *(uint4*)(dp + 8) = o1;
}

// ---------------------------------------------------------------------------
// GEMM: C[M,N] = A[M,K] * Bt[N,K]^T, bf16 in, fp32 accum.
// 128x128 block tile, 4 waves (2x2 of 64x64), MFMA 16x16x32_bf16, BK=32.
// 2-PHASE double-buffered pipeline: stage tile t+1 via global_load_lds into
// buf^1 BEFORE computing tile t; single barrier per K-step.
template <bool OUT_F32>
__global__ __launch_bounds__(256) void gemm_bt(const u16* __restrict__ A,
                                               const u16* __restrict__ Bt,
                                               void* __restrict__ Cp,
                                               int M, int N, int K) {
  __shared__ u16 As[2][128 * 32];
  __shared__ u16 Bs[2][128 * 32];
  int tid  = threadIdx.x;
  int lane = tid & 63, wave = tid >> 6;
  int wr = wave >> 1, wc = wave & 1;
  int col = lane & 15, quad = lane >> 4;
  int m0 = blockIdx.y * 128, n0 = blockIdx.x * 128;

  v4f acc[4][4];
#pragma unroll
  for (int mi = 0; mi < 4; mi++)
#pragma unroll
    for (int ni = 0; ni < 4; ni++) acc[mi][ni] = (v4f){0.f, 0.f, 0.f, 0.f};

  int srow = tid >> 2;            // 0..63
  int skc  = (tid & 3) * 8;       // 0,8,16,24
  const u16* ag0 = A  + (size_t)(m0 + srow) * K + skc;
  const u16* ag1 = ag0 + (size_t)64 * K;
  const u16* bg0 = Bt + (size_t)(n0 + srow) * K + skc;
  const u16* bg1 = bg0 + (size_t)64 * K;

  // prologue: stage tile 0 into buffer 0
  gld_lds16(ag0, &As[0][tid * 8]);
  gld_lds16(ag1, &As[0][2048 + tid * 8]);
  gld_lds16(bg0, &Bs[0][tid * 8]);
  gld_lds16(bg1, &Bs[0][2048 + tid * 8]);
  __syncthreads();

  int nt = K >> 5;
  for (int t = 0; t < nt; ++t) {
    int cur = t & 1, nxt = cur ^ 1;
    if (t + 1 < nt) {
      int k0 = (t + 1) << 5;
      gld_lds16(ag0 + k0, &As[nxt][tid * 8]);
      gld_lds16(ag1 + k0, &As[nxt][2048 + tid * 8]);
      gld_lds16(bg0 + k0, &Bs[nxt][tid * 8]);
      gld_lds16(bg1 + k0, &Bs[nxt][2048 + tid * 8]);
    }
    v8bf a[4], bb[4];
#pragma unroll
    for (int mi = 0; mi < 4; mi++)
      a[mi] = *(const v8bf*)&As[cur][(wr * 64 + mi * 16 + col) * 32 + quad * 8];
#pragma unroll
    for (int ni = 0; ni < 4; ni++)
      bb[ni] = *(const v8bf*)&Bs[cur][(wc * 64 + ni * 16 + col) * 32 + quad * 8];
    __builtin_amdgcn_s_setprio(1);
#pragma unroll
    for (int mi = 0; mi < 4; mi++)
#pragma unroll
      for (int ni = 0; ni < 4; ni++)
        acc[mi][ni] = __builtin_amdgcn_mfma_f32_16x16x32_bf16(a[mi], bb[ni], acc[mi][ni], 0, 0, 0);
    __builtin_amdgcn_s_setprio(0);
    __syncthreads();   // drains stage (vmcnt 0) + protects buf reuse
  }

  // epilogue: C/D layout row = quad*4+reg, col = lane&15
#pragma unroll
  for (int mi = 0; mi < 4; mi++)
#pragma unroll
    for (int ni = 0; ni < 4; ni++) {
      int r_ = m0 + wr * 64 + mi * 16 + quad * 4;
      int c_ = n0 + wc * 64 + ni * 16 + col;
#pragma unroll
      for (int r = 0; r < 4; r++) {
        if (OUT_F32) ((float*)Cp)[(size_t)(r_ + r) * N + c_] = acc[mi][ni][r];
        else         ((u16*)Cp)[(size_t)(r_ + r) * N + c_]   = f2bf(acc[mi][ni][r]);
      }
    }
}

// ---------------------------------------------------------------------------
// RMS-norm (+ 1+w) + RoPE. q normed IN PLACE in qkv_raw; k written to
// head-major kf. One wave per (token, head-row).
__global__ __launch_bounds__(256) void norm_rope(u16* __restrict__ qkv,
                                                 const float* __restrict__ cosb,
                                                 const float* __restrict__ sinb,
                                                 const float* __restrict__ qw,
                                                 const float* __restrict__ kw,
                                                 u16* __restrict__ kf) {
  int wave = threadIdx.x >> 6, lane = threadIdx.x & 63;
  int tw = blockIdx.x * 4 + wave;
  int token = tw / 20, r = tw % 20;
  const u16* src;
  u16* dst;
  const float* wptr;
  if (r < 16) {
    src  = qkv + (size_t)token * QKVW + r * 256;       // q of head r
    dst  = (u16*)src;                                  // in place
    wptr = qw;
  } else {
    src  = qkv + (size_t)token * QKVW + 4096 + (r - 16) * HDIM;
    int b = token >> 11, s = token & (SEQ - 1);
    dst  = kf + ((size_t)(b * NKV + (r - 16)) * SEQ + s) * HDIM;
    wptr = kw;
  }
  int d0 = lane * 2;
  u32 x = *(const u32*)(src + d0);
  float x0 = bf2f((u16)(x & 0xffff)), x1 = bf2f((u16)(x >> 16));
  float ss = x0 * x0 + x1 * x1;
#pragma unroll
  for (int off = 1; off < 64; off <<= 1) ss += __shfl_xor(ss, off, 64);
  float sc = rsqrtf(ss * (1.f / 128.f) + 1e-6f);
  float y0 = bf2f(f2bf(x0 * sc * (1.f + wptr[d0])));
  float y1 = bf2f(f2bf(x1 * sc * (1.f + wptr[d0 + 1])));
  float p0 = __shfl_xor(y0, 8, 64);
  float p1 = __shfl_xor(y1, 8, 64);
  float z0 = y0, z1 = y1;
  if (lane < 16) {
    float c0 = cosb[(size_t)token * 32 + d0];
    float c1 = cosb[(size_t)token * 32 + d0 + 1];
    float s0 = sinb[(size_t)token * 32 + d0];
    float s1 = sinb[(size_t)token * 32 + d0 + 1];
    if (lane < 8) { z0 = y0 * c0 - p0 * s0; z1 = y1 * c1 - p1 * s1; }
    else          { z0 = y0 * c0 + p0 * s0; z1 = y1 * c1 + p1 * s1; }
  }
  u32 outp = (u32)f2bf(z0) | ((u32)f2bf(z1) << 16);
  *(u32*)(dst + d0) = outp;
}

// ---------------------------------------------------------------------------
// Causal GQA flash attention + sigmoid-gate epilogue.
// Swapped-operand QK^T (mfma(K,Q)), in-register softmax, sigma-permuted V
// (R2 structure, synchronous staging — T14 reverted: it spilled to scratch).
// QBLK=128: 8 waves x 16 q-rows share each K/V tile (staging cost per MFMA
// halves; K/V HBM re-fetch halves; 512-thread blocks, same 39.9KB LDS).
// grid (16, NHEAD, NB), block 512.
__global__ __launch_bounds__(512) void attn_kernel(const u16* __restrict__ qkv,
                                                   const u16* __restrict__ kf,
                                                   const u16* __restrict__ vt,
                                                   u16* __restrict__ ga) {
  __shared__ u16 ks[64 * 136];      // K-tile [key][d], stride 136
  __shared__ u16 vs[128 * 88];      // V-tile [d][sigma(key)], stride 88
  int tid = threadIdx.x, lane = tid & 63, wave = tid >> 6;   // wave 0..7
  int col = lane & 15, quad = lane >> 4;
  int qt = 15 - blockIdx.x;         // heavy causal blocks first (LPT)
  int h = blockIdx.y, b = blockIdx.z;
  int g = h >> 2;
  int qw0 = qt * 128 + wave * 16;
  int myq = qw0 + col;              // this lane's query row
  const float scl2 = 0.08838834764831845f * 1.4426950408889634f;  // D^-.5 * log2e

  // Q fragments (B-layout: n=query=lane&15, k=quad*8+j)
  v8bf qfr[4];
  const u16* qbase = qkv + (size_t)(b * SEQ + myq) * QKVW + h * 256 + quad * 8;
#pragma unroll
  for (int kc = 0; kc < 4; kc++) qfr[kc] = *(const v8bf*)(qbase + kc * 32);

  v4f o[8];                         // O^T: o[dt][r] = O[d=16dt+4*quad+r][myq]
#pragma unroll
  for (int nt = 0; nt < 8; nt++) o[nt] = (v4f){0.f, 0.f, 0.f, 0.f};
  float l = 0.f;                    // per-quad partial row-sum (this lane's keys)
  float m = -1e30f;                 // running max (uniform across quads)

  const u16* kfb = kf + (size_t)(b * NKV + g) * SEQ * HDIM;
  const u16* vtb = vt + (size_t)(b * NKV + g) * HDIM * SEQ;

  // staging maps, 512 threads, 2 passes each
  int ksr = tid >> 4, ksd = (tid & 15) * 8;   // K: rows p*32+ksr (0..63)
  int vsd = tid >> 3, w8 = tid & 7;           // V: d = p*64+vsd (0..127)
  // sigma(s)=(s5,s3,s2,s4,s1,s0); src s = 8*w8 + i, w8 bits = (s5,s4,s3)
  int voff = 32 * ((w8 >> 2) & 1) + 16 * (w8 & 1) + 4 * ((w8 >> 1) & 1);
  int vsrc = w8 * 8;

  int nk = 2 * qt + 2;              // K/V tiles of 64 covering keys <= qt*128+127
  for (int it = 0; it < nk; it++) {
    int k0 = it * 64;
    __syncthreads();  // previous iteration's LDS reads complete
#pragma unroll
    for (int p = 0; p < 2; p++)
      *(uint4*)&ks[(p * 32 + ksr) * 136 + ksd] =
          *(const uint4*)&kfb[(size_t)(k0 + p * 32 + ksr) * HDIM + ksd];
#pragma unroll
    for (int p = 0; p < 2; p++) {
      int d = p * 64 + vsd;
      uint4 gv = *(const uint4*)&vtb[(size_t)d * SEQ + k0 + vsrc];
      uint2 w0 = {gv.x, gv.y};
      uint2 w1 = {gv.z, gv.w};
      *(uint2*)&vs[d * 88 + voff]     = w0;   // keys i=0..3 -> voff..voff+3
      *(uint2*)&vs[d * 88 + voff + 8] = w1;   // keys i=4..7 -> voff+8..
    }
    __syncthreads();

    // --- S^T = K Q^T: st[t][r] = S[key=k0+16t+4*quad+r][myq] ---
    v4f st[4];
    __builtin_amdgcn_s_setprio(1);
#pragma unroll
    for (int t = 0; t < 4; t++) {
      v4f acc = (v4f){0.f, 0.f, 0.f, 0.f};
#pragma unroll
      for (int kc = 0; kc < 4; kc++) {
        v8bf kfr = *(const v8bf*)&ks[(t * 16 + col) * 136 + kc * 32 + quad * 8];
        acc = __builtin_amdgcn_mfma_f32_16x16x32_bf16(kfr, qfr[kc], acc, 0, 0, 0);
      }
      st[t] = acc;
    }
    __builtin_amdgcn_s_setprio(0);

    // --- in-register online softmax (exp2 domain) ---
    bool maskw = (k0 + 63 > qw0);   // wave-uniform: any key can exceed a row
    float pmax = -1e30f;
#pragma unroll
    for (int t = 0; t < 4; t++)
#pragma unroll
      for (int r = 0; r < 4; r++) {
        float x = st[t][r] * scl2;
        if (maskw && (k0 + t * 16 + quad * 4 + r > myq)) x = -1e30f;
        st[t][r] = x;
        pmax = fmaxf(pmax, x);
      }
    pmax = fmaxf(pmax, __shfl_xor(pmax, 16, 64));
    pmax = fmaxf(pmax, __shfl_xor(pmax, 32, 64));
    if (__any(pmax > m + 8.f)) {         // defer-max: rescale only on growth
      float nm = fmaxf(m, pmax);
      float al = exp2f(m - nm);
      m = nm;
#pragma unroll
      for (int nt = 0; nt < 8; nt++)
#pragma unroll
        for (int r = 0; r < 4; r++) o[nt][r] *= al;
      l *= al;
    }
    // P in bf16, packed directly in PV B-fragment order (lane-local)
    v8bf pb0, pb1;
    float ls = 0.f;
#pragma unroll
    for (int t = 0; t < 4; t++)
#pragma unroll
      for (int r = 0; r < 4; r++) {
        float p = exp2f(st[t][r] - m);
        ls += p;
        if (t < 2) pb0[t * 4 + r] = (__bf16)p;
        else       pb1[(t - 2) * 4 + r] = (__bf16)p;
      }
    l += ls;

    // --- O^T += V^T P : A=V-frag (m=d), B=P-frag (n=query) ---
    __builtin_amdgcn_s_setprio(1);
#pragma unroll
    for (int nt = 0; nt < 8; nt++) {
      v8bf vb0 = *(const v8bf*)&vs[(nt * 16 + col) * 88 + quad * 8];
      v8bf vb1 = *(const v8bf*)&vs[(nt * 16 + col) * 88 + 32 + quad * 8];
      o[nt] = __builtin_amdgcn_mfma_f32_16x16x32_bf16(vb0, pb0, o[nt], 0, 0, 0);
      o[nt] = __builtin_amdgcn_mfma_f32_16x16x32_bf16(vb1, pb1, o[nt], 0, 0, 0);
    }
    __builtin_amdgcn_s_setprio(0);
  }

  // --- final row-sum across quads, normalize, sigmoid-gate, store ---
  l += __shfl_xor(l, 16, 64);
  l += __shfl_xor(l, 32, 64);
  float inv = 1.f / l;
  const u16* gb = qkv + (size_t)(b * SEQ + myq) * QKVW + h * 256 + 128 + quad * 4;
  u16* ob = ga + (size_t)(b * SEQ + myq) * 2048 + h * HDIM + quad * 4;
#pragma unroll
  for (int nt = 0; nt < 8; nt++) {
    uint2 gw = *(const uint2*)(gb + nt * 16);
    float g0 = bf2f((u16)(gw.x & 0xffff)), g1 = bf2f((u16)(gw.x >> 16));
    float g2 = bf2f((u16)(gw.y & 0xffff)), g3 = bf2f((u16)(gw.y >> 16));
    float a0 = o[nt][0] * inv * (1.f / (1.f + expf(-g0)));
    float a1 = o[nt][1] * inv * (1.f / (1.f + expf(-g1)));
    float a2 = o[nt][2] * inv * (1.f / (1.f + expf(-g2)));
    float a3 = o[nt][3] * inv * (1.f / (1.f + expf(-g3)));
    uint2 ow;
    ow.x = (u32)f2bf(a0) | ((u32)f2bf(a1) << 16);
    ow.y = (u32)f2bf(a2) | ((u32)f2bf(a3) << 16);
    *(uint2*)(ob + nt * 16) = ow;
  }
}

// ---------------------------------------------------------------------------
extern "C" void kernel_launch(void* const* d_in, const int* in_sizes, int n_in,
                              void* d_out, int out_size, void* d_ws, size_t ws_size,
                              hipStream_t stream) {
  const float* hidden = (const float*)d_in[0];
  const float* cosb   = (const float*)d_in[1];
  const float* sinb   = (const float*)d_in[2];
  // d_in[3] attention_mask: exact causal triu(-1e9) -> applied analytically
  const float* wq  = (const float*)d_in[4];
  const float* wk  = (const float*)d_in[5];
  const float* wv  = (const float*)d_in[6];
  const float* wo  = (const float*)d_in[7];
  const float* qnw = (const float*)d_in[8];
  const float* knw = (const float*)d_in[9];
  float* out = (float*)d_out;

  u16* ws      = (u16*)d_ws;
  u16* qkv_raw = ws;
  u16* region2 = qkv_raw + (size_t)8192 * QKVW;
  u16* region3 = region2 + (size_t)8192 * 2048;
  u16* hidden_bf = region2;
  u16* g_attn    = region2;
  u16* bt_qkv    = region3;
  u16* vt        = region3;
  u16* bt_wo     = region3 + (size_t)4194304;
  u16* k_f       = region3 + (size_t)8388608;

  // 1) convert hidden fp32 -> bf16
  conv_f32_bf16<<<dim3(8192), 256, 0, stream>>>(hidden, hidden_bf);
  // 2) convert+transpose qkv weights into B^T bf16 (wq|wk|wv row-concat)
  transpose_w<<<dim3(64, 32), 256, 0, stream>>>(wq, bt_qkv, 2048, 4096);
  transpose_w<<<dim3(8, 32), 256, 0, stream>>>(wk, bt_qkv + (size_t)4096 * 2048, 2048, 512);
  transpose_w<<<dim3(8, 32), 256, 0, stream>>>(wv, bt_qkv + (size_t)4608 * 2048, 2048, 512);
  // 3) fused QKV projection (bf16 out)
  gemm_bt<false><<<dim3(QKVW / 128, 8192 / 128), 256, 0, stream>>>(hidden_bf, bt_qkv, qkv_raw, 8192, QKVW, 2048);
  // 4) RMS-norm + RoPE: q in place, k -> head-major k_f
  norm_rope<<<dim3(8192 * 20 / 4), 256, 0, stream>>>(qkv_raw, cosb, sinb, qnw, knw, k_f);
  // 5) V -> d-major vt (overwrites dead bt_qkv)
  transpose_v<<<dim3(SEQ / 64, HDIM / 64, NB * NKV), 256, 0, stream>>>(qkv_raw, vt);
  // 6) convert+transpose wo
  transpose_w<<<dim3(32, 32), 256, 0, stream>>>(wo, bt_wo, 2048, 2048);
  // 7) causal flash attention + gating (writes g_attn over dead hidden_bf)
  attn_kernel<<<dim3(16, NHEAD, NB), 512, 0, stream>>>(qkv_raw, k_f, vt, g_attn);
  // 8) output projection, fp32 store
  gemm_bt<true><<<dim3(2048 / 128, 8192 / 128), 256, 0, stream>>>(g_attn, bt_wo, out, 8192, 2048, 2048);
}

// Round 6
// 684.612 us; speedup vs baseline: 1.3220x; 1.0629x over previous
//
#include <hip/hip_runtime.h>

// Problem constants
#define SEQ   2048
#define NHEAD 16
#define NKV   4
#define HDIM  128
#define NB    4
// qkv_raw row layout: [qg 0..4095 | k 4096..4607 | v 4608..5119]
#define QKVW  5120

typedef unsigned short u16;
typedef unsigned int   u32;
typedef __bf16 v8bf __attribute__((ext_vector_type(8)));
typedef float  v4f  __attribute__((ext_vector_type(4)));

__device__ __forceinline__ u16 f2bf(float f) {
  u32 u = __float_as_uint(f);
  u += 0x7fffu + ((u >> 16) & 1u);
  return (u16)(u >> 16);
}
__device__ __forceinline__ float bf2f(u16 b) {
  return __uint_as_float(((u32)b) << 16);
}

// Async global->LDS DMA, 16B per lane. LDS dest must be linear in lane order
// (wave-uniform base + lane*16).
__device__ __forceinline__ void gld_lds16(const u16* g, u16* l) {
  __builtin_amdgcn_global_load_lds(
      (const __attribute__((address_space(1))) u32*)(unsigned long long)(uintptr_t)g,
      (__attribute__((address_space(3))) u32*)(u32)(uintptr_t)l,
      16, 0, 0);
}

// ---------------------------------------------------------------------------
// fp32 -> bf16 bulk convert (8 elems/thread)
__global__ __launch_bounds__(256) void conv_f32_bf16(const float* __restrict__ s,
                                                     u16* __restrict__ d) {
  size_t i = ((size_t)blockIdx.x * 256 + threadIdx.x) * 8;
  float4 a = *(const float4*)(s + i);
  float4 b = *(const float4*)(s + i + 4);
  uint4 o;
  o.x = (u32)f2bf(a.x) | ((u32)f2bf(a.y) << 16);
  o.y = (u32)f2bf(a.z) | ((u32)f2bf(a.w) << 16);
  o.z = (u32)f2bf(b.x) | ((u32)f2bf(b.y) << 16);
  o.w = (u32)f2bf(b.z) | ((u32)f2bf(b.w) << 16);
  *(uint4*)(d + i) = o;
}

// ---------------------------------------------------------------------------
// fp32 source -> bf16 transposed dst: dst[c*R + r] = bf16(src[r*C + c])
// grid (C/64, R/64), block 256.
__global__ __launch_bounds__(256) void transpose_w(const float* __restrict__ src,
                                                   u16* __restrict__ dst,
                                                   int R, int C) {
  __shared__ u16 tile[64][80];
  int t = threadIdx.x;
  int r0 = blockIdx.y * 64, c0 = blockIdx.x * 64;
  int rr = t >> 2, cc = (t & 3) * 16;
  const float* sp = src + (size_t)(r0 + rr) * C + c0 + cc;
  float4 f0 = *(const float4*)sp;
  float4 f1 = *(const float4*)(sp + 4);
  float4 f2 = *(const float4*)(sp + 8);
  float4 f3 = *(const float4*)(sp + 12);
  u16* tp = &tile[rr][cc];
  tp[0] = f2bf(f0.x);  tp[1] = f2bf(f0.y);  tp[2] = f2bf(f0.z);  tp[3] = f2bf(f0.w);
  tp[4] = f2bf(f1.x);  tp[5] = f2bf(f1.y);  tp[6] = f2bf(f1.z);  tp[7] = f2bf(f1.w);
  tp[8] = f2bf(f2.x);  tp[9] = f2bf(f2.y);  tp[10] = f2bf(f2.z); tp[11] = f2bf(f2.w);
  tp[12] = f2bf(f3.x); tp[13] = f2bf(f3.y); tp[14] = f2bf(f3.z); tp[15] = f2bf(f3.w);
  __syncthreads();
  int cr = t >> 2, rc = (t & 3) * 16;
  u32 pk[8];
#pragma unroll
  for (int i = 0; i < 8; i++) {
    u32 lo = tile[rc + 2 * i][cr];
    u32 hi = tile[rc + 2 * i + 1][cr];
    pk[i] = lo | (hi << 16);
  }
  u16* dp = dst + (size_t)(c0 + cr) * R + r0 + rc;
  uint4 o0 = {pk[0], pk[1], pk[2], pk[3]};
  uint4 o1 = {pk[4], pk[5], pk[6], pk[7]};
  *(uint4*)dp       = o0;
  *(uint4*)(dp + 8) = o1;
}

// ---------------------------------------------------------------------------
// V transpose (bf16->bf16): vt[((b*NKV+g)*HDIM + d)*SEQ + s]
// grid (SEQ/64, HDIM/64, NB*NKV), block 256
__global__ __launch_bounds__(256) void transpose_v(const u16* __restrict__ qkv,
                                                   u16* __restrict__ vt) {
  __shared__ u16 tile[64][80];
  int t = threadIdx.x;
  int s0 = blockIdx.x * 64;
  int d0 = blockIdx.y * 64;
  int bg = blockIdx.z;
  int b = bg >> 2, g = bg & 3;
  int sr = t >> 2, dc = (t & 3) * 16;
  const u16* sp = qkv + (size_t)(b * SEQ + s0 + sr) * QKVW + 4608 + g * HDIM + d0 + dc;
  *(uint4*)&tile[sr][dc]     = *(const uint4*)sp;
  *(uint4*)&tile[sr][dc + 8] = *(const uint4*)(sp + 8);
  __syncthreads();
  int dr = t >> 2, sc = (t & 3) * 16;
  u32 pk[8];
#pragma unroll
  for (int i = 0; i < 8; i++) {
    u32 lo = tile[sc + 2 * i][dr];
    u32 hi = tile[sc + 2 * i + 1][dr];
    pk[i] = lo | (hi << 16);
  }
  u16* dp = vt + ((size_t)bg * HDIM + d0 + dr) * SEQ + s0 + sc;
  uint4 o0 = {pk[0], pk[1], pk[2], pk[3]};
  uint4 o1 = {pk[4], pk[5], pk[6], pk[7]};
  *(uint4*)dp       = o0;
  *(uint4*)(dp + 8) = o1;
}

// ---------------------------------------------------------------------------
// GEMM: C[M,N] = A[M,K] * Bt[N,K]^T, bf16 in, fp32 accum.
// 256x256 block tile, 8 waves (2x4 of 128x64), MFMA 16x16x32_bf16, BK=32.
// 3-buffer LDS ring + COUNTED vmcnt pipeline (T3/T4): iter t computes
// buf[t%3], stages tile t+2 into buf[(t+2)%3] via global_load_lds, then
// "s_waitcnt vmcnt(4); s_barrier" — tile t+1's loads verified landed, tile
// t+2's 4 loads stay IN FLIGHT across the barrier (never drained to 0 in
// the main loop). Hazards: RAW covered by vmcnt(4)+barrier (all waves have
// waited their own loads before any wave reads); WAR covered by the
// previous iteration's barrier (reads of a buffer complete before it is
// re-staged two iterations later). Epilogue: vmcnt(0) at t>=NT-2.
// BK=32 keeps linear LDS at the ds_read_b128 bank floor (8 lanes/16B slot)
// and keeps global_load_lds destinations legal-linear (no swizzle needed).
// 1-D grid with XCD swizzle (nwg % 8 == 0 in our launches).
template <bool OUT_F32>
__global__ __launch_bounds__(512, 2) void gemm_bt(const u16* __restrict__ A,
                                                  const u16* __restrict__ Bt,
                                                  void* __restrict__ Cp,
                                                  int M, int N, int K) {
  __shared__ u16 As[3][256 * 32];
  __shared__ u16 Bs[3][256 * 32];
  int tid  = threadIdx.x;
  int lane = tid & 63, wave = tid >> 6;
  int wr = wave >> 2, wc = wave & 3;          // 2 x 4 wave grid
  int col = lane & 15, quad = lane >> 4;
  // XCD-aware block swizzle (bijective: nwg % 8 == 0)
  int nwg = gridDim.x;
  int cpx = nwg >> 3;
  int id  = blockIdx.x;
  int idp = (id & 7) * cpx + (id >> 3);
  int ntile = N >> 8;
  int m0 = (idp / ntile) << 8;
  int n0 = (idp % ntile) << 8;

  v4f acc[8][4];
#pragma unroll
  for (int mi = 0; mi < 8; mi++)
#pragma unroll
    for (int ni = 0; ni < 4; ni++) acc[mi][ni] = (v4f){0.f, 0.f, 0.f, 0.f};

  // staging map: thread covers row tid>>2 (sweep +128), col8 (tid&3)*8
  int srow = tid >> 2;            // 0..127
  int skc  = (tid & 3) * 8;       // 0,8,16,24
  const u16* ag = A  + (size_t)(m0 + srow) * K + skc;
  const u16* bg = Bt + (size_t)(n0 + srow) * K + skc;
  const size_t rowK128 = (size_t)128 * K;

#define STAGE(buf, k0)                                        \
  do {                                                        \
    gld_lds16(ag + (k0),           &As[buf][tid * 8]);        \
    gld_lds16(ag + rowK128 + (k0), &As[buf][4096 + tid * 8]); \
    gld_lds16(bg + (k0),           &Bs[buf][tid * 8]);        \
    gld_lds16(bg + rowK128 + (k0), &Bs[buf][4096 + tid * 8]); \
  } while (0)

  // prologue: tiles 0 and 1 in flight; wait tile 0 only (oldest 4)
  STAGE(0, 0);
  STAGE(1, 32);
  asm volatile("s_waitcnt vmcnt(4)\n\ts_barrier" ::: "memory");

  const int NT = K >> 5;
  int cb = 0;                      // buffer holding tile t
  for (int t = 0; t < NT; ++t) {
    int sb = cb + 2 >= 3 ? cb - 1 : cb + 2;   // (t+2)%3
    if (t + 2 < NT) {
      int k0 = (t + 2) << 5;
      STAGE(sb, k0);
    }
    // fragment reads (linear layout, bank-floor)
    v8bf bfr[4];
#pragma unroll
    for (int ni = 0; ni < 4; ni++)
      bfr[ni] = *(const v8bf*)&Bs[cb][(wc * 64 + ni * 16 + col) * 32 + quad * 8];
    __builtin_amdgcn_s_setprio(1);
#pragma unroll
    for (int mi = 0; mi < 8; mi++) {
      v8bf a = *(const v8bf*)&As[cb][(wr * 128 + mi * 16 + col) * 32 + quad * 8];
#pragma unroll
      for (int ni = 0; ni < 4; ni++)
        acc[mi][ni] = __builtin_amdgcn_mfma_f32_16x16x32_bf16(a, bfr[ni], acc[mi][ni], 0, 0, 0);
    }
    __builtin_amdgcn_s_setprio(0);
    if (t < NT - 2) asm volatile("s_waitcnt vmcnt(4)\n\ts_barrier" ::: "memory");
    else            asm volatile("s_waitcnt vmcnt(0)\n\ts_barrier" ::: "memory");
    cb = cb + 1 >= 3 ? 0 : cb + 1;
  }
#undef STAGE

  // epilogue: C/D layout row = quad*4+reg, col = lane&15
#pragma unroll
  for (int mi = 0; mi < 8; mi++)
#pragma unroll
    for (int ni = 0; ni < 4; ni++) {
      int r_ = m0 + wr * 128 + mi * 16 + quad * 4;
      int c_ = n0 + wc * 64 + ni * 16 + col;
#pragma unroll
      for (int r = 0; r < 4; r++) {
        if (OUT_F32) ((float*)Cp)[(size_t)(r_ + r) * N + c_] = acc[mi][ni][r];
        else         ((u16*)Cp)[(size_t)(r_ + r) * N + c_]   = f2bf(acc[mi][ni][r]);
      }
    }
}

// ---------------------------------------------------------------------------
// RMS-norm (+ 1+w) + RoPE. q normed IN PLACE in qkv_raw; k written to
// head-major kf. One wave per (token, head-row).
__global__ __launch_bounds__(256) void norm_rope(u16* __restrict__ qkv,
                                                 const float* __restrict__ cosb,
                                                 const float* __restrict__ sinb,
                                                 const float* __restrict__ qw,
                                                 const float* __restrict__ kw,
                                                 u16* __restrict__ kf) {
  int wave = threadIdx.x >> 6, lane = threadIdx.x & 63;
  int tw = blockIdx.x * 4 + wave;
  int token = tw / 20, r = tw % 20;
  const u16* src;
  u16* dst;
  const float* wptr;
  if (r < 16) {
    src  = qkv + (size_t)token * QKVW + r * 256;       // q of head r
    dst  = (u16*)src;                                  // in place
    wptr = qw;
  } else {
    src  = qkv + (size_t)token * QKVW + 4096 + (r - 16) * HDIM;
    int b = token >> 11, s = token & (SEQ - 1);
    dst  = kf + ((size_t)(b * NKV + (r - 16)) * SEQ + s) * HDIM;
    wptr = kw;
  }
  int d0 = lane * 2;
  u32 x = *(const u32*)(src + d0);
  float x0 = bf2f((u16)(x & 0xffff)), x1 = bf2f((u16)(x >> 16));
  float ss = x0 * x0 + x1 * x1;
#pragma unroll
  for (int off = 1; off < 64; off <<= 1) ss += __shfl_xor(ss, off, 64);
  float sc = rsqrtf(ss * (1.f / 128.f) + 1e-6f);
  float y0 = bf2f(f2bf(x0 * sc * (1.f + wptr[d0])));
  float y1 = bf2f(f2bf(x1 * sc * (1.f + wptr[d0 + 1])));
  float p0 = __shfl_xor(y0, 8, 64);
  float p1 = __shfl_xor(y1, 8, 64);
  float z0 = y0, z1 = y1;
  if (lane < 16) {
    float c0 = cosb[(size_t)token * 32 + d0];
    float c1 = cosb[(size_t)token * 32 + d0 + 1];
    float s0 = sinb[(size_t)token * 32 + d0];
    float s1 = sinb[(size_t)token * 32 + d0 + 1];
    if (lane < 8) { z0 = y0 * c0 - p0 * s0; z1 = y1 * c1 - p1 * s1; }
    else          { z0 = y0 * c0 + p0 * s0; z1 = y1 * c1 + p1 * s1; }
  }
  u32 outp = (u32)f2bf(z0) | ((u32)f2bf(z1) << 16);
  *(u32*)(dst + d0) = outp;
}

// ---------------------------------------------------------------------------
// Causal GQA flash attention + sigmoid-gate epilogue (R5 structure, kept).
// Swapped-operand QK^T (mfma(K,Q)), in-register softmax, sigma-permuted V.
// QBLK=128: 8 waves x 16 q-rows share each K/V tile.
// grid (16, NHEAD, NB), block 512.
__global__ __launch_bounds__(512) void attn_kernel(const u16* __restrict__ qkv,
                                                   const u16* __restrict__ kf,
                                                   const u16* __restrict__ vt,
                                                   u16* __restrict__ ga) {
  __shared__ u16 ks[64 * 136];      // K-tile [key][d], stride 136
  __shared__ u16 vs[128 * 88];      // V-tile [d][sigma(key)], stride 88
  int tid = threadIdx.x, lane = tid & 63, wave = tid >> 6;   // wave 0..7
  int col = lane & 15, quad = lane >> 4;
  int qt = 15 - blockIdx.x;         // heavy causal blocks first (LPT)
  int h = blockIdx.y, b = blockIdx.z;
  int g = h >> 2;
  int qw0 = qt * 128 + wave * 16;
  int myq = qw0 + col;              // this lane's query row
  const float scl2 = 0.08838834764831845f * 1.4426950408889634f;  // D^-.5 * log2e

  // Q fragments (B-layout: n=query=lane&15, k=quad*8+j)
  v8bf qfr[4];
  const u16* qbase = qkv + (size_t)(b * SEQ + myq) * QKVW + h * 256 + quad * 8;
#pragma unroll
  for (int kc = 0; kc < 4; kc++) qfr[kc] = *(const v8bf*)(qbase + kc * 32);

  v4f o[8];                         // O^T: o[dt][r] = O[d=16dt+4*quad+r][myq]
#pragma unroll
  for (int nt = 0; nt < 8; nt++) o[nt] = (v4f){0.f, 0.f, 0.f, 0.f};
  float l = 0.f;                    // per-quad partial row-sum (this lane's keys)
  float m = -1e30f;                 // running max (uniform across quads)

  const u16* kfb = kf + (size_t)(b * NKV + g) * SEQ * HDIM;
  const u16* vtb = vt + (size_t)(b * NKV + g) * HDIM * SEQ;

  // staging maps, 512 threads, 2 passes each
  int ksr = tid >> 4, ksd = (tid & 15) * 8;   // K: rows p*32+ksr (0..63)
  int vsd = tid >> 3, w8 = tid & 7;           // V: d = p*64+vsd (0..127)
  // sigma(s)=(s5,s3,s2,s4,s1,s0); src s = 8*w8 + i, w8 bits = (s5,s4,s3)
  int voff = 32 * ((w8 >> 2) & 1) + 16 * (w8 & 1) + 4 * ((w8 >> 1) & 1);
  int vsrc = w8 * 8;

  int nk = 2 * qt + 2;              // K/V tiles of 64 covering keys <= qt*128+127
  for (int it = 0; it < nk; it++) {
    int k0 = it * 64;
    __syncthreads();  // previous iteration's LDS reads complete
#pragma unroll
    for (int p = 0; p < 2; p++)
      *(uint4*)&ks[(p * 32 + ksr) * 136 + ksd] =
          *(const uint4*)&kfb[(size_t)(k0 + p * 32 + ksr) * HDIM + ksd];
#pragma unroll
    for (int p = 0; p < 2; p++) {
      int d = p * 64 + vsd;
      uint4 gv = *(const uint4*)&vtb[(size_t)d * SEQ + k0 + vsrc];
      uint2 w0 = {gv.x, gv.y};
      uint2 w1 = {gv.z, gv.w};
      *(uint2*)&vs[d * 88 + voff]     = w0;   // keys i=0..3 -> voff..voff+3
      *(uint2*)&vs[d * 88 + voff + 8] = w1;   // keys i=4..7 -> voff+8..
    }
    __syncthreads();

    // --- S^T = K Q^T: st[t][r] = S[key=k0+16t+4*quad+r][myq] ---
    v4f st[4];
    __builtin_amdgcn_s_setprio(1);
#pragma unroll
    for (int t = 0; t < 4; t++) {
      v4f acc = (v4f){0.f, 0.f, 0.f, 0.f};
#pragma unroll
      for (int kc = 0; kc < 4; kc++) {
        v8bf kfr = *(const v8bf*)&ks[(t * 16 + col) * 136 + kc * 32 + quad * 8];
        acc = __builtin_amdgcn_mfma_f32_16x16x32_bf16(kfr, qfr[kc], acc, 0, 0, 0);
      }
      st[t] = acc;
    }
    __builtin_amdgcn_s_setprio(0);

    // --- in-register online softmax (exp2 domain) ---
    bool maskw = (k0 + 63 > qw0);   // wave-uniform: any key can exceed a row
    float pmax = -1e30f;
#pragma unroll
    for (int t = 0; t < 4; t++)
#pragma unroll
      for (int r = 0; r < 4; r++) {
        float x = st[t][r] * scl2;
        if (maskw && (k0 + t * 16 + quad * 4 + r > myq)) x = -1e30f;
        st[t][r] = x;
        pmax = fmaxf(pmax, x);
      }
    pmax = fmaxf(pmax, __shfl_xor(pmax, 16, 64));
    pmax = fmaxf(pmax, __shfl_xor(pmax, 32, 64));
    if (__any(pmax > m + 8.f)) {         // defer-max: rescale only on growth
      float nm = fmaxf(m, pmax);
      float al = exp2f(m - nm);
      m = nm;
#pragma unroll
      for (int nt = 0; nt < 8; nt++)
#pragma unroll
        for (int r = 0; r < 4; r++) o[nt][r] *= al;
      l *= al;
    }
    // P in bf16, packed directly in PV B-fragment order (lane-local)
    v8bf pb0, pb1;
    float ls = 0.f;
#pragma unroll
    for (int t = 0; t < 4; t++)
#pragma unroll
      for (int r = 0; r < 4; r++) {
        float p = exp2f(st[t][r] - m);
        ls += p;
        if (t < 2) pb0[t * 4 + r] = (__bf16)p;
        else       pb1[(t - 2) * 4 + r] = (__bf16)p;
      }
    l += ls;

    // --- O^T += V^T P : A=V-frag (m=d), B=P-frag (n=query) ---
    __builtin_amdgcn_s_setprio(1);
#pragma unroll
    for (int nt = 0; nt < 8; nt++) {
      v8bf vb0 = *(const v8bf*)&vs[(nt * 16 + col) * 88 + quad * 8];
      v8bf vb1 = *(const v8bf*)&vs[(nt * 16 + col) * 88 + 32 + quad * 8];
      o[nt] = __builtin_amdgcn_mfma_f32_16x16x32_bf16(vb0, pb0, o[nt], 0, 0, 0);
      o[nt] = __builtin_amdgcn_mfma_f32_16x16x32_bf16(vb1, pb1, o[nt], 0, 0, 0);
    }
    __builtin_amdgcn_s_setprio(0);
  }

  // --- final row-sum across quads, normalize, sigmoid-gate, store ---
  l += __shfl_xor(l, 16, 64);
  l += __shfl_xor(l, 32, 64);
  float inv = 1.f / l;
  const u16* gb = qkv + (size_t)(b * SEQ + myq) * QKVW + h * 256 + 128 + quad * 4;
  u16* ob = ga + (size_t)(b * SEQ + myq) * 2048 + h * HDIM + quad * 4;
#pragma unroll
  for (int nt = 0; nt < 8; nt++) {
    uint2 gw = *(const uint2*)(gb + nt * 16);
    float g0 = bf2f((u16)(gw.x & 0xffff)), g1 = bf2f((u16)(gw.x >> 16));
    float g2 = bf2f((u16)(gw.y & 0xffff)), g3 = bf2f((u16)(gw.y >> 16));
    float a0 = o[nt][0] * inv * (1.f / (1.f + expf(-g0)));
    float a1 = o[nt][1] * inv * (1.f / (1.f + expf(-g1)));
    float a2 = o[nt][2] * inv * (1.f / (1.f + expf(-g2)));
    float a3 = o[nt][3] * inv * (1.f / (1.f + expf(-g3)));
    uint2 ow;
    ow.x = (u32)f2bf(a0) | ((u32)f2bf(a1) << 16);
    ow.y = (u32)f2bf(a2) | ((u32)f2bf(a3) << 16);
    *(uint2*)(ob + nt * 16) = ow;
  }
}

// ---------------------------------------------------------------------------
extern "C" void kernel_launch(void* const* d_in, const int* in_sizes, int n_in,
                              void* d_out, int out_size, void* d_ws, size_t ws_size,
                              hipStream_t stream) {
  const float* hidden = (const float*)d_in[0];
  const float* cosb   = (const float*)d_in[1];
  const float* sinb   = (const float*)d_in[2];
  // d_in[3] attention_mask: exact causal triu(-1e9) -> applied analytically
  const float* wq  = (const float*)d_in[4];
  const float* wk  = (const float*)d_in[5];
  const float* wv  = (const float*)d_in[6];
  const float* wo  = (const float*)d_in[7];
  const float* qnw = (const float*)d_in[8];
  const float* knw = (const float*)d_in[9];
  float* out = (float*)d_out;

  u16* ws      = (u16*)d_ws;
  u16* qkv_raw = ws;
  u16* region2 = qkv_raw + (size_t)8192 * QKVW;
  u16* region3 = region2 + (size_t)8192 * 2048;
  u16* hidden_bf = region2;
  u16* g_attn    = region2;
  u16* bt_qkv    = region3;
  u16* vt        = region3;
  u16* bt_wo     = region3 + (size_t)4194304;
  u16* k_f       = region3 + (size_t)8388608;

  // 1) convert hidden fp32 -> bf16
  conv_f32_bf16<<<dim3(8192), 256, 0, stream>>>(hidden, hidden_bf);
  // 2) convert+transpose qkv weights into B^T bf16 (wq|wk|wv row-concat)
  transpose_w<<<dim3(64, 32), 256, 0, stream>>>(wq, bt_qkv, 2048, 4096);
  transpose_w<<<dim3(8, 32), 256, 0, stream>>>(wk, bt_qkv + (size_t)4096 * 2048, 2048, 512);
  transpose_w<<<dim3(8, 32), 256, 0, stream>>>(wv, bt_qkv + (size_t)4608 * 2048, 2048, 512);
  // 3) fused QKV projection (bf16 out): grid 32x20 = 640 blocks (640%8==0)
  gemm_bt<false><<<dim3(640), 512, 0, stream>>>(hidden_bf, bt_qkv, qkv_raw, 8192, QKVW, 2048);
  // 4) RMS-norm + RoPE: q in place, k -> head-major k_f
  norm_rope<<<dim3(8192 * 20 / 4), 256, 0, stream>>>(qkv_raw, cosb, sinb, qnw, knw, k_f);
  // 5) V -> d-major vt (overwrites dead bt_qkv)
  transpose_v<<<dim3(SEQ / 64, HDIM / 64, NB * NKV), 256, 0, stream>>>(qkv_raw, vt);
  // 6) convert+transpose wo
  transpose_w<<<dim3(32, 32), 256, 0, stream>>>(wo, bt_wo, 2048, 2048);
  // 7) causal flash attention + gating (writes g_attn over dead hidden_bf)
  attn_kernel<<<dim3(16, NHEAD, NB), 512, 0, stream>>>(qkv_raw, k_f, vt, g_attn);
  // 8) output projection, fp32 store: grid 32x8 = 256 blocks (256%8==0)
  gemm_bt<true><<<dim3(256), 512, 0, stream>>>(g_attn, bt_wo, out, 8192, 2048, 2048);
}